// Round 1
// baseline (1082.390 us; speedup 1.0000x reference)
//
#include <hip/hip_runtime.h>

#define N_NODES 50000
#define N_EDGES 800000
#define D 96
#define CHUNKS (D / 4)   // 24 float4 chunks per row

// ---------------------------------------------------------------------------
// Kernel 1: zero the hidden accumulator (d_ws is poisoned, must self-zero)
// ---------------------------------------------------------------------------
__global__ void zero_f32(float* __restrict__ p, long long n) {
    long long i = (long long)blockIdx.x * blockDim.x + threadIdx.x;
    long long stride = (long long)gridDim.x * blockDim.x;
    for (; i < n; i += stride) p[i] = 0.0f;
}

// ---------------------------------------------------------------------------
// Kernel 2: scatter-add  hidden[row[e]] += edge_w[e] * x[col[e]]
// thread t -> edge e = t/CHUNKS, chunk c = t%CHUNKS (24 consecutive threads
// read one contiguous 384B source row -> coalesced gather)
// ---------------------------------------------------------------------------
__global__ __launch_bounds__(256) void scatter_edges(
        const float* __restrict__ x,
        const float* __restrict__ edge_w,
        const int*   __restrict__ row,
        const int*   __restrict__ col,
        float*       __restrict__ hidden) {
    long long t = (long long)blockIdx.x * blockDim.x + threadIdx.x;
    const long long total = (long long)N_EDGES * CHUNKS;
    if (t >= total) return;
    int e = (int)(t / CHUNKS);
    int c = (int)(t % CHUNKS);
    int src = col[e];
    int dst = row[e];
    float w = edge_w[e];
    const float4 v = *reinterpret_cast<const float4*>(&x[(long long)src * D + c * 4]);
    float* o = &hidden[(long long)dst * D + c * 4];
    atomicAdd(o + 0, w * v.x);
    atomicAdd(o + 1, w * v.y);
    atomicAdd(o + 2, w * v.z);
    atomicAdd(o + 3, w * v.w);
}

// ---------------------------------------------------------------------------
// Kernel 3: out = relu(hidden @ W + bias), W staged in LDS (96x96 f32 = 36.8KB)
// one thread per output element, grid-stride
// ---------------------------------------------------------------------------
__global__ __launch_bounds__(256) void gemm_bias_relu(
        const float* __restrict__ hidden,
        const float* __restrict__ W,
        const float* __restrict__ bias,
        float*       __restrict__ out) {
    __shared__ float Ws[D * D];
    __shared__ float bs[D];
    for (int i = threadIdx.x; i < D * D; i += blockDim.x) Ws[i] = W[i];
    if (threadIdx.x < D) bs[threadIdx.x] = bias[threadIdx.x];
    __syncthreads();

    const long long total = (long long)N_NODES * D;
    long long stride = (long long)gridDim.x * blockDim.x;
    for (long long idx = (long long)blockIdx.x * blockDim.x + threadIdx.x;
         idx < total; idx += stride) {
        int n = (int)(idx / D);
        int d = (int)(idx % D);
        const float* hrow = &hidden[(long long)n * D];
        float acc = bs[d];
        #pragma unroll
        for (int k = 0; k < D; ++k) {
            acc = fmaf(hrow[k], Ws[k * D + d], acc);
        }
        out[idx] = fmaxf(acc, 0.0f);
    }
}

extern "C" void kernel_launch(void* const* d_in, const int* in_sizes, int n_in,
                              void* d_out, int out_size, void* d_ws, size_t ws_size,
                              hipStream_t stream) {
    const float* x      = (const float*)d_in[0];
    const float* edge_w = (const float*)d_in[1];
    const float* weight = (const float*)d_in[2];
    const float* bias   = (const float*)d_in[3];
    const int*   row    = (const int*)d_in[4];
    const int*   col    = (const int*)d_in[5];
    float* out    = (float*)d_out;
    float* hidden = (float*)d_ws;   // N_NODES * D floats = 19.2 MB

    const long long hidden_elems = (long long)N_NODES * D;

    // 1) zero accumulator
    {
        int blocks = 2048;
        zero_f32<<<blocks, 256, 0, stream>>>(hidden, hidden_elems);
    }
    // 2) scatter-add edges
    {
        long long total = (long long)N_EDGES * CHUNKS;
        int blocks = (int)((total + 255) / 256);
        scatter_edges<<<blocks, 256, 0, stream>>>(x, edge_w, row, col, hidden);
    }
    // 3) dense GEMM + bias + relu
    {
        int blocks = 2048;
        gemm_bias_relu<<<blocks, 256, 0, stream>>>(hidden, weight, bias, out);
    }
}

// Round 2
// 224.006 us; speedup vs baseline: 4.8320x; 4.8320x over previous
//
#include <hip/hip_runtime.h>

#define N_NODES 50000
#define N_EDGES 800000
#define D 96
#define D4 (D / 4)          // 24 float4 chunks per row
#define SCAN_BLK 256
#define NBLK ((N_NODES + SCAN_BLK - 1) / SCAN_BLK)   // 196

// ===========================================================================
// Fast path: transform-first + CSR build + atomic-free aggregation
// ===========================================================================

// y = x @ W   (W staged in LDS; one thread per output element)
__global__ __launch_bounds__(256) void transform_xw(
        const float* __restrict__ x, const float* __restrict__ W,
        float* __restrict__ y) {
    __shared__ float Ws[D * D];
    for (int i = threadIdx.x; i < D * D; i += blockDim.x) Ws[i] = W[i];
    __syncthreads();
    const long long total = (long long)N_NODES * D;
    long long stride = (long long)gridDim.x * blockDim.x;
    for (long long idx = (long long)blockIdx.x * blockDim.x + threadIdx.x;
         idx < total; idx += stride) {
        int n = (int)(idx / D);
        int d = (int)(idx % D);
        const float* xr = &x[(long long)n * D];
        float acc = 0.0f;
        #pragma unroll
        for (int k = 0; k < D; ++k) acc = fmaf(xr[k], Ws[k * D + d], acc);
        y[idx] = acc;
    }
}

__global__ void zero_i32(int* __restrict__ p, int n) {
    int i = blockIdx.x * blockDim.x + threadIdx.x;
    if (i < n) p[i] = 0;
}

__global__ void hist_rows(const int* __restrict__ row, int* __restrict__ counts) {
    int e = blockIdx.x * blockDim.x + threadIdx.x;
    if (e < N_EDGES) atomicAdd(&counts[row[e]], 1);
}

// per-256-chunk sums of counts
__global__ __launch_bounds__(SCAN_BLK) void scan_block_sums(
        const int* __restrict__ counts, int* __restrict__ blockSums) {
    __shared__ int s[SCAN_BLK];
    int i = blockIdx.x * SCAN_BLK + threadIdx.x;
    s[threadIdx.x] = (i < N_NODES) ? counts[i] : 0;
    for (int off = SCAN_BLK / 2; off > 0; off >>= 1) {
        __syncthreads();
        if (threadIdx.x < off) s[threadIdx.x] += s[threadIdx.x + off];
    }
    if (threadIdx.x == 0) blockSums[blockIdx.x] = s[0];
}

// exclusive scan of blockSums (NBLK <= 256) in one block
__global__ __launch_bounds__(SCAN_BLK) void scan_prefix(int* __restrict__ blockSums) {
    __shared__ int s[SCAN_BLK];
    int t = threadIdx.x;
    int v = (t < NBLK) ? blockSums[t] : 0;
    s[t] = v;
    for (int off = 1; off < SCAN_BLK; off <<= 1) {
        __syncthreads();
        int a = (t >= off) ? s[t - off] : 0;
        __syncthreads();
        s[t] += a;
    }
    if (t < NBLK) blockSums[t] = s[t] - v;   // exclusive
}

// final scan: offsets[i] (CSR starts) and cursor[i] (scatter write pointers)
__global__ __launch_bounds__(SCAN_BLK) void scan_final(
        const int* __restrict__ counts, const int* __restrict__ blockSums,
        int* __restrict__ offsets, int* __restrict__ cursor) {
    __shared__ int s[SCAN_BLK];
    int t = threadIdx.x;
    int i = blockIdx.x * SCAN_BLK + t;
    int c = (i < N_NODES) ? counts[i] : 0;
    s[t] = c;
    for (int off = 1; off < SCAN_BLK; off <<= 1) {
        __syncthreads();
        int a = (t >= off) ? s[t - off] : 0;
        __syncthreads();
        s[t] += a;
    }
    if (i < N_NODES) {
        int excl = blockSums[blockIdx.x] + s[t] - c;
        offsets[i] = excl;
        cursor[i]  = excl;
        if (i == N_NODES - 1) offsets[N_NODES] = excl + c;
    }
}

// bucket-scatter (col, w) records into CSR order
__global__ void scatter_sort(const int* __restrict__ row, const int* __restrict__ col,
                             const float* __restrict__ edge_w,
                             int* __restrict__ cursor, int2* __restrict__ sorted) {
    int e = blockIdx.x * blockDim.x + threadIdx.x;
    if (e >= N_EDGES) return;
    int r = row[e];
    int pos = atomicAdd(&cursor[r], 1);
    sorted[pos] = make_int2(col[e], __float_as_int(edge_w[e]));
}

// out[n] = relu( sum_j w_j * y[col_j] + bias ), 24 threads (float4 chunks) per node
__global__ __launch_bounds__(256) void aggregate(
        const float* __restrict__ y, const int* __restrict__ offsets,
        const int2* __restrict__ sorted, const float* __restrict__ bias,
        float* __restrict__ out) {
    int t = blockIdx.x * blockDim.x + threadIdx.x;
    const int total = N_NODES * D4;
    if (t >= total) return;
    int n = t / D4;
    int c = t % D4;
    int beg = offsets[n];
    int end = offsets[n + 1];
    const float4* y4 = reinterpret_cast<const float4*>(y);
    float4 acc = make_float4(0.f, 0.f, 0.f, 0.f);
    for (int j = beg; j < end; ++j) {
        int2 rec = sorted[j];
        float w = __int_as_float(rec.y);
        float4 v = y4[(long long)rec.x * D4 + c];
        acc.x = fmaf(w, v.x, acc.x);
        acc.y = fmaf(w, v.y, acc.y);
        acc.z = fmaf(w, v.z, acc.z);
        acc.w = fmaf(w, v.w, acc.w);
    }
    float4 b4 = reinterpret_cast<const float4*>(bias)[c];
    float4 o;
    o.x = fmaxf(acc.x + b4.x, 0.f);
    o.y = fmaxf(acc.y + b4.y, 0.f);
    o.z = fmaxf(acc.z + b4.z, 0.f);
    o.w = fmaxf(acc.w + b4.w, 0.f);
    reinterpret_cast<float4*>(out)[t] = o;
}

// ===========================================================================
// Fallback path (round-1 proven): atomic scatter into hidden, then GEMM
// ===========================================================================
__global__ void zero_f32(float* __restrict__ p, long long n) {
    long long i = (long long)blockIdx.x * blockDim.x + threadIdx.x;
    long long stride = (long long)gridDim.x * blockDim.x;
    for (; i < n; i += stride) p[i] = 0.0f;
}

__global__ __launch_bounds__(256) void scatter_edges(
        const float* __restrict__ x, const float* __restrict__ edge_w,
        const int* __restrict__ row, const int* __restrict__ col,
        float* __restrict__ hidden) {
    long long t = (long long)blockIdx.x * blockDim.x + threadIdx.x;
    const long long total = (long long)N_EDGES * D4;
    if (t >= total) return;
    int e = (int)(t / D4);
    int c = (int)(t % D4);
    float w = edge_w[e];
    const float4 v = *reinterpret_cast<const float4*>(&x[(long long)col[e] * D + c * 4]);
    float* o = &hidden[(long long)row[e] * D + c * 4];
    atomicAdd(o + 0, w * v.x);
    atomicAdd(o + 1, w * v.y);
    atomicAdd(o + 2, w * v.z);
    atomicAdd(o + 3, w * v.w);
}

__global__ __launch_bounds__(256) void gemm_bias_relu(
        const float* __restrict__ hidden, const float* __restrict__ W,
        const float* __restrict__ bias, float* __restrict__ out) {
    __shared__ float Ws[D * D];
    __shared__ float bs[D];
    for (int i = threadIdx.x; i < D * D; i += blockDim.x) Ws[i] = W[i];
    if (threadIdx.x < D) bs[threadIdx.x] = bias[threadIdx.x];
    __syncthreads();
    const long long total = (long long)N_NODES * D;
    long long stride = (long long)gridDim.x * blockDim.x;
    for (long long idx = (long long)blockIdx.x * blockDim.x + threadIdx.x;
         idx < total; idx += stride) {
        int n = (int)(idx / D);
        int d = (int)(idx % D);
        const float* hrow = &hidden[(long long)n * D];
        float acc = bs[d];
        #pragma unroll
        for (int k = 0; k < D; ++k) acc = fmaf(hrow[k], Ws[k * D + d], acc);
        out[idx] = fmaxf(acc, 0.0f);
    }
}

// ===========================================================================
extern "C" void kernel_launch(void* const* d_in, const int* in_sizes, int n_in,
                              void* d_out, int out_size, void* d_ws, size_t ws_size,
                              hipStream_t stream) {
    const float* x      = (const float*)d_in[0];
    const float* edge_w = (const float*)d_in[1];
    const float* weight = (const float*)d_in[2];
    const float* bias   = (const float*)d_in[3];
    const int*   row    = (const int*)d_in[4];
    const int*   col    = (const int*)d_in[5];
    float* out = (float*)d_out;

    // workspace layout (8B-aligned pieces)
    const size_t yBytes      = (size_t)N_NODES * D * sizeof(float);   // 19,200,000
    const size_t sortedBytes = (size_t)N_EDGES * sizeof(int2);        //  6,400,000
    const size_t countsBytes = (size_t)N_NODES * sizeof(int);
    const size_t offsBytes   = (size_t)(N_NODES + 1) * sizeof(int);
    const size_t cursorBytes = (size_t)N_NODES * sizeof(int);
    const size_t bsumsBytes  = (size_t)SCAN_BLK * sizeof(int);
    const size_t need = yBytes + sortedBytes + countsBytes + offsBytes +
                        cursorBytes + bsumsBytes + 64;

    if (ws_size >= need) {
        char* wsb = (char*)d_ws;
        float* y        = (float*)wsb;                 wsb += yBytes;
        int2*  sorted   = (int2*)wsb;                  wsb += sortedBytes;
        int*   counts   = (int*)wsb;                   wsb += countsBytes;
        int*   offsets  = (int*)wsb;                   wsb += offsBytes;
        int*   cursor   = (int*)wsb;                   wsb += cursorBytes;
        int*   bsums    = (int*)wsb;

        transform_xw<<<2048, 256, 0, stream>>>(x, weight, y);
        zero_i32<<<(N_NODES + 255) / 256, 256, 0, stream>>>(counts, N_NODES);
        hist_rows<<<(N_EDGES + 255) / 256, 256, 0, stream>>>(row, counts);
        scan_block_sums<<<NBLK, SCAN_BLK, 0, stream>>>(counts, bsums);
        scan_prefix<<<1, SCAN_BLK, 0, stream>>>(bsums);
        scan_final<<<NBLK, SCAN_BLK, 0, stream>>>(counts, bsums, offsets, cursor);
        scatter_sort<<<(N_EDGES + 255) / 256, 256, 0, stream>>>(row, col, edge_w,
                                                                cursor, sorted);
        aggregate<<<(N_NODES * D4 + 255) / 256, 256, 0, stream>>>(y, offsets, sorted,
                                                                  bias, out);
    } else {
        // fallback: proven round-1 path (needs only 19.2 MB)
        float* hidden = (float*)d_ws;
        const long long hidden_elems = (long long)N_NODES * D;
        zero_f32<<<2048, 256, 0, stream>>>(hidden, hidden_elems);
        long long total = (long long)N_EDGES * D4;
        scatter_edges<<<(int)((total + 255) / 256), 256, 0, stream>>>(x, edge_w, row,
                                                                      col, hidden);
        gemm_bias_relu<<<2048, 256, 0, stream>>>(hidden, weight, bias, out);
    }
}

// Round 3
// 183.379 us; speedup vs baseline: 5.9025x; 1.2215x over previous
//
#include <hip/hip_runtime.h>

#define N_NODES 50000
#define N_EDGES 800000
#define D 96
#define D4 (D / 4)          // 24 float4 chunks per row
#define DHALF 48            // outputs per thread in transform
#define SCAN_BLK 256
#define NBLK ((N_NODES + SCAN_BLK - 1) / SCAN_BLK)   // 196

// ===========================================================================
// transform: y = x @ W
// one thread per (node, half-of-outputs). acc[48] in VGPRs, W read with
// wave-uniform addresses (only loop counters + blockIdx.y) -> s_load path.
// ===========================================================================
__global__ __launch_bounds__(256) void transform_xw(
        const float* __restrict__ x, const float* __restrict__ W,
        float* __restrict__ y) {
    int n = blockIdx.x * blockDim.x + threadIdx.x;
    if (n >= N_NODES) return;
    const int dbase = blockIdx.y * DHALF;   // 0 or 48, wave-uniform

    const float4* x4 = reinterpret_cast<const float4*>(x) + (long long)n * D4;

    float acc[DHALF];
    #pragma unroll
    for (int d = 0; d < DHALF; ++d) acc[d] = 0.0f;

    for (int kk = 0; kk < D4; ++kk) {           // 24 iterations, not unrolled
        float4 xv = x4[kk];
        const float* Wr = &W[(kk * 4) * D + dbase];   // wave-uniform address
        #pragma unroll
        for (int d = 0; d < DHALF; ++d) {
            acc[d] = fmaf(xv.x, Wr[d],         acc[d]);
            acc[d] = fmaf(xv.y, Wr[D + d],     acc[d]);
            acc[d] = fmaf(xv.z, Wr[2 * D + d], acc[d]);
            acc[d] = fmaf(xv.w, Wr[3 * D + d], acc[d]);
        }
    }

    float4* yo = reinterpret_cast<float4*>(y) + (long long)n * D4 + blockIdx.y * (DHALF / 4);
    #pragma unroll
    for (int d = 0; d < DHALF / 4; ++d)
        yo[d] = make_float4(acc[4 * d], acc[4 * d + 1], acc[4 * d + 2], acc[4 * d + 3]);
}

// ===========================================================================
// CSR build
// ===========================================================================
__global__ void zero_i32(int* __restrict__ p, int n) {
    int i = blockIdx.x * blockDim.x + threadIdx.x;
    if (i < n) p[i] = 0;
}

__global__ void hist_rows(const int* __restrict__ row, int* __restrict__ counts) {
    int e = blockIdx.x * blockDim.x + threadIdx.x;
    if (e < N_EDGES) atomicAdd(&counts[row[e]], 1);
}

__global__ __launch_bounds__(SCAN_BLK) void scan_block_sums(
        const int* __restrict__ counts, int* __restrict__ blockSums) {
    __shared__ int s[SCAN_BLK];
    int i = blockIdx.x * SCAN_BLK + threadIdx.x;
    s[threadIdx.x] = (i < N_NODES) ? counts[i] : 0;
    for (int off = SCAN_BLK / 2; off > 0; off >>= 1) {
        __syncthreads();
        if (threadIdx.x < off) s[threadIdx.x] += s[threadIdx.x + off];
    }
    if (threadIdx.x == 0) blockSums[blockIdx.x] = s[0];
}

__global__ __launch_bounds__(SCAN_BLK) void scan_prefix(int* __restrict__ blockSums) {
    __shared__ int s[SCAN_BLK];
    int t = threadIdx.x;
    int v = (t < NBLK) ? blockSums[t] : 0;
    s[t] = v;
    for (int off = 1; off < SCAN_BLK; off <<= 1) {
        __syncthreads();
        int a = (t >= off) ? s[t - off] : 0;
        __syncthreads();
        s[t] += a;
    }
    if (t < NBLK) blockSums[t] = s[t] - v;   // exclusive
}

__global__ __launch_bounds__(SCAN_BLK) void scan_final(
        const int* __restrict__ counts, const int* __restrict__ blockSums,
        int* __restrict__ offsets, int* __restrict__ cursor) {
    __shared__ int s[SCAN_BLK];
    int t = threadIdx.x;
    int i = blockIdx.x * SCAN_BLK + t;
    int c = (i < N_NODES) ? counts[i] : 0;
    s[t] = c;
    for (int off = 1; off < SCAN_BLK; off <<= 1) {
        __syncthreads();
        int a = (t >= off) ? s[t - off] : 0;
        __syncthreads();
        s[t] += a;
    }
    if (i < N_NODES) {
        int excl = blockSums[blockIdx.x] + s[t] - c;
        offsets[i] = excl;
        cursor[i]  = excl;
        if (i == N_NODES - 1) offsets[N_NODES] = excl + c;
    }
}

__global__ void scatter_sort(const int* __restrict__ row, const int* __restrict__ col,
                             const float* __restrict__ edge_w,
                             int* __restrict__ cursor, int2* __restrict__ sorted) {
    int e = blockIdx.x * blockDim.x + threadIdx.x;
    if (e >= N_EDGES) return;
    int r = row[e];
    int pos = atomicAdd(&cursor[r], 1);
    sorted[pos] = make_int2(col[e], __float_as_int(edge_w[e]));
}

// ===========================================================================
// aggregate: out[n] = relu( sum_j w_j * y[col_j] + bias )
// 24 threads (float4 chunks) per node; edge loop unrolled x2 for MLP
// ===========================================================================
__global__ __launch_bounds__(256) void aggregate(
        const float* __restrict__ y, const int* __restrict__ offsets,
        const int2* __restrict__ sorted, const float* __restrict__ bias,
        float* __restrict__ out) {
    int t = blockIdx.x * blockDim.x + threadIdx.x;
    const int total = N_NODES * D4;
    if (t >= total) return;
    int n = t / D4;
    int c = t % D4;
    int beg = offsets[n];
    int end = offsets[n + 1];
    const float4* y4 = reinterpret_cast<const float4*>(y);
    float4 acc = make_float4(0.f, 0.f, 0.f, 0.f);
    float4 acc2 = make_float4(0.f, 0.f, 0.f, 0.f);
    int j = beg;
    for (; j + 1 < end; j += 2) {
        int2 r0 = sorted[j];
        int2 r1 = sorted[j + 1];
        float w0 = __int_as_float(r0.y);
        float w1 = __int_as_float(r1.y);
        float4 v0 = y4[(long long)r0.x * D4 + c];
        float4 v1 = y4[(long long)r1.x * D4 + c];
        acc.x = fmaf(w0, v0.x, acc.x);
        acc.y = fmaf(w0, v0.y, acc.y);
        acc.z = fmaf(w0, v0.z, acc.z);
        acc.w = fmaf(w0, v0.w, acc.w);
        acc2.x = fmaf(w1, v1.x, acc2.x);
        acc2.y = fmaf(w1, v1.y, acc2.y);
        acc2.z = fmaf(w1, v1.z, acc2.z);
        acc2.w = fmaf(w1, v1.w, acc2.w);
    }
    if (j < end) {
        int2 r0 = sorted[j];
        float w0 = __int_as_float(r0.y);
        float4 v0 = y4[(long long)r0.x * D4 + c];
        acc.x = fmaf(w0, v0.x, acc.x);
        acc.y = fmaf(w0, v0.y, acc.y);
        acc.z = fmaf(w0, v0.z, acc.z);
        acc.w = fmaf(w0, v0.w, acc.w);
    }
    acc.x += acc2.x; acc.y += acc2.y; acc.z += acc2.z; acc.w += acc2.w;
    float4 b4 = reinterpret_cast<const float4*>(bias)[c];
    float4 o;
    o.x = fmaxf(acc.x + b4.x, 0.f);
    o.y = fmaxf(acc.y + b4.y, 0.f);
    o.z = fmaxf(acc.z + b4.z, 0.f);
    o.w = fmaxf(acc.w + b4.w, 0.f);
    reinterpret_cast<float4*>(out)[t] = o;
}

// ===========================================================================
// Fallback path (round-1 proven): atomic scatter into hidden, then GEMM
// ===========================================================================
__global__ void zero_f32(float* __restrict__ p, long long n) {
    long long i = (long long)blockIdx.x * blockDim.x + threadIdx.x;
    long long stride = (long long)gridDim.x * blockDim.x;
    for (; i < n; i += stride) p[i] = 0.0f;
}

__global__ __launch_bounds__(256) void scatter_edges(
        const float* __restrict__ x, const float* __restrict__ edge_w,
        const int* __restrict__ row, const int* __restrict__ col,
        float* __restrict__ hidden) {
    long long t = (long long)blockIdx.x * blockDim.x + threadIdx.x;
    const long long total = (long long)N_EDGES * D4;
    if (t >= total) return;
    int e = (int)(t / D4);
    int c = (int)(t % D4);
    float w = edge_w[e];
    const float4 v = *reinterpret_cast<const float4*>(&x[(long long)col[e] * D + c * 4]);
    float* o = &hidden[(long long)row[e] * D + c * 4];
    atomicAdd(o + 0, w * v.x);
    atomicAdd(o + 1, w * v.y);
    atomicAdd(o + 2, w * v.z);
    atomicAdd(o + 3, w * v.w);
}

__global__ __launch_bounds__(256) void gemm_bias_relu(
        const float* __restrict__ hidden, const float* __restrict__ W,
        const float* __restrict__ bias, float* __restrict__ out) {
    __shared__ float Ws[D * D];
    __shared__ float bs[D];
    for (int i = threadIdx.x; i < D * D; i += blockDim.x) Ws[i] = W[i];
    if (threadIdx.x < D) bs[threadIdx.x] = bias[threadIdx.x];
    __syncthreads();
    const long long total = (long long)N_NODES * D;
    long long stride = (long long)gridDim.x * blockDim.x;
    for (long long idx = (long long)blockIdx.x * blockDim.x + threadIdx.x;
         idx < total; idx += stride) {
        int n = (int)(idx / D);
        int d = (int)(idx % D);
        const float* hrow = &hidden[(long long)n * D];
        float acc = bs[d];
        #pragma unroll
        for (int k = 0; k < D; ++k) acc = fmaf(hrow[k], Ws[k * D + d], acc);
        out[idx] = fmaxf(acc, 0.0f);
    }
}

// ===========================================================================
extern "C" void kernel_launch(void* const* d_in, const int* in_sizes, int n_in,
                              void* d_out, int out_size, void* d_ws, size_t ws_size,
                              hipStream_t stream) {
    const float* x      = (const float*)d_in[0];
    const float* edge_w = (const float*)d_in[1];
    const float* weight = (const float*)d_in[2];
    const float* bias   = (const float*)d_in[3];
    const int*   row    = (const int*)d_in[4];
    const int*   col    = (const int*)d_in[5];
    float* out = (float*)d_out;

    const size_t yBytes      = (size_t)N_NODES * D * sizeof(float);   // 19,200,000
    const size_t sortedBytes = (size_t)N_EDGES * sizeof(int2);        //  6,400,000
    const size_t countsBytes = (size_t)N_NODES * sizeof(int);
    const size_t offsBytes   = (size_t)(N_NODES + 1) * sizeof(int);
    const size_t cursorBytes = (size_t)N_NODES * sizeof(int);
    const size_t bsumsBytes  = (size_t)SCAN_BLK * sizeof(int);
    const size_t need = yBytes + sortedBytes + countsBytes + offsBytes +
                        cursorBytes + bsumsBytes + 64;

    if (ws_size >= need) {
        char* wsb = (char*)d_ws;
        float* y        = (float*)wsb;                 wsb += yBytes;
        int2*  sorted   = (int2*)wsb;                  wsb += sortedBytes;
        int*   counts   = (int*)wsb;                   wsb += countsBytes;
        int*   offsets  = (int*)wsb;                   wsb += offsBytes;
        int*   cursor   = (int*)wsb;                   wsb += cursorBytes;
        int*   bsums    = (int*)wsb;

        dim3 tgrid((N_NODES + 255) / 256, 2);
        transform_xw<<<tgrid, 256, 0, stream>>>(x, weight, y);
        zero_i32<<<(N_NODES + 255) / 256, 256, 0, stream>>>(counts, N_NODES);
        hist_rows<<<(N_EDGES + 255) / 256, 256, 0, stream>>>(row, counts);
        scan_block_sums<<<NBLK, SCAN_BLK, 0, stream>>>(counts, bsums);
        scan_prefix<<<1, SCAN_BLK, 0, stream>>>(bsums);
        scan_final<<<NBLK, SCAN_BLK, 0, stream>>>(counts, bsums, offsets, cursor);
        scatter_sort<<<(N_EDGES + 255) / 256, 256, 0, stream>>>(row, col, edge_w,
                                                                cursor, sorted);
        aggregate<<<(N_NODES * D4 + 255) / 256, 256, 0, stream>>>(y, offsets, sorted,
                                                                  bias, out);
    } else {
        float* hidden = (float*)d_ws;
        const long long hidden_elems = (long long)N_NODES * D;
        zero_f32<<<2048, 256, 0, stream>>>(hidden, hidden_elems);
        long long total = (long long)N_EDGES * D4;
        scatter_edges<<<(int)((total + 255) / 256), 256, 0, stream>>>(x, edge_w, row,
                                                                      col, hidden);
        gemm_bias_relu<<<2048, 256, 0, stream>>>(hidden, weight, bias, out);
    }
}